// Round 7
// baseline (763.948 us; speedup 1.0000x reference)
//
#include <hip/hip_runtime.h>

typedef unsigned short u16;
typedef unsigned int u32;
typedef float f32x4 __attribute__((ext_vector_type(4)));
typedef __bf16 bf16x8 __attribute__((ext_vector_type(8)));

#define M_ALL 155648.0f
#define GP 168            // k_gram xsT pitch (u16): 84 dw stride -> 8-quad spread, 16B aligned

__device__ __forceinline__ u16 f2bf(float f) {
  union { float f; u32 u; } x; x.f = f;
  u32 u = x.u;
  u += 0x7FFFu + ((u >> 16) & 1u);   // RNE
  return (u16)(u >> 16);
}
__device__ __forceinline__ float bf2f(u16 h) {
  union { u32 u; float f; } x; x.u = ((u32)h) << 16;
  return x.f;
}
__device__ __forceinline__ f32x4 zero4() { f32x4 z = {0.f, 0.f, 0.f, 0.f}; return z; }

// xs swizzled index: row m (0..151), col c (0..255), 16B chunks XORed with m&7
__device__ __forceinline__ int xs_idx(int m, int c) {
  return m * 256 + ((((c >> 3) ^ (m & 7)) << 3) | (c & 7));
}
// Y2 swizzled index: row r (0..511), col kvp (0..63), chunk ^= (r&7)^((r>>3)&7)
__device__ __forceinline__ int y2_idx(int r, int kvp) {
  int sw = (r & 7) ^ ((r >> 3) & 7);
  return r * 64 + ((((kvp >> 3) ^ sw) << 3) | (kvp & 7));
}

// ---------- prep: L2-normalize adjacency rows, build wa2[g][w(20)][kvp(64)] bf16 ----------
__global__ void k_prep(const float* __restrict__ para, u16* __restrict__ wa2) {
  __shared__ float aL[3 * 8 * 19 * 19];
  int tid = threadIdx.x;
  if (tid < 456) {                                        // 3*8*19 rows
    int k = tid / 152, rem = tid % 152, g = rem / 19, v = rem % 19;
    int base = ((k * 8 + g) * 19 + v) * 19;
    float ss = 0.f;
    #pragma unroll
    for (int w = 0; w < 19; ++w) { float a = para[base + w]; ss += a * a; }
    float inv = 1.f / (sqrtf(ss) + 1e-4f);
    #pragma unroll
    for (int w = 0; w < 19; ++w) aL[base + w] = para[base + w] * inv;
  }
  __syncthreads();
  for (int i = tid; i < 8 * 20 * 64; i += 512) {
    int g = i / 1280, rem = i % 1280, w = rem >> 6, kvp = rem & 63;
    u16 val = 0;
    if (w < 19 && kvp < 57) {
      int k = kvp / 19, v = kvp - 19 * k;
      val = f2bf(aL[((k * 8 + g) * 19 + v) * 19 + w]);
    }
    wa2[i] = val;
  }
}

// ---------- transpose linear_weight (256x768 f32) -> Wt[d][c] bf16 ----------
__global__ void k_wt(const float* __restrict__ W, u16* __restrict__ wt) {
  int idx = blockIdx.x * 512 + threadIdx.x;   // exactly 196608
  int d = idx >> 8, c = idx & 255;
  wt[idx] = f2bf(W[c * 768 + d]);
}

// ---------- tr: x f32 -> xbf (row-major bf16) + xT (col-major bf16) + colsum ----------
// Tile 64 m x 256 c per block, 256 threads. Lane-major-m loads (L1 absorbs the 4-way
// line reuse across waves) make the LDS transpose writes conflict-free (bank = l/2).
// Replaces k_cvt AND kills k_gram's scalar-gather staging (the round-6 lesson: that
// staging was load-issue bound, so halving bytes didn't help; vectorizing does).
__global__ __launch_bounds__(256) void k_tr(const float* __restrict__ x,
                                            u16* __restrict__ xbf,
                                            u16* __restrict__ xT,
                                            float* __restrict__ colsum) {
  __shared__ u16 tl[256 * 64];     // [c][m_local], 32 KB
  __shared__ float csl[256];
  int t = threadIdx.x;
  int l = t & 63, w = t >> 6;
  size_t m0 = (size_t)blockIdx.x * 64;
  int m = (int)m0 + l;
  const float4* xr = reinterpret_cast<const float4*>(x + (size_t)m * 256);
  #pragma unroll 1
  for (int it = 0; it < 16; ++it) {
    int c4 = 4 * w + 16 * it;                    // covers all multiples of 4 in [0,256)
    float4 f = xr[c4 >> 2];
    u16 b0 = f2bf(f.x), b1 = f2bf(f.y), b2 = f2bf(f.z), b3 = f2bf(f.w);
    ushort4 pk; pk.x = b0; pk.y = b1; pk.z = b2; pk.w = b3;
    *reinterpret_cast<ushort4*>(xbf + (size_t)m * 256 + c4) = pk;  // L2 merges 8B stores
    tl[(c4 + 0) * 64 + l] = b0;                  // bank = l/2: conflict-free
    tl[(c4 + 1) * 64 + l] = b1;
    tl[(c4 + 2) * 64 + l] = b2;
    tl[(c4 + 3) * 64 + l] = b3;
  }
  __syncthreads();
  // write xT rows (16B granules) + colsum partials (f32 sums of bf16 values)
  #pragma unroll 1
  for (int pass = 0; pass < 8; ++pass) {
    int c = (t >> 3) + 32 * pass;                // each c covered exactly once per block
    int g = t & 7;
    bf16x8 v = *reinterpret_cast<const bf16x8*>(&tl[c * 64 + g * 8]);
    *reinterpret_cast<bf16x8*>(&xT[(size_t)c * 155648 + m0 + g * 8]) = v;
    union { bf16x8 v8; u16 u[8]; } uv; uv.v8 = v;
    float s = 0.f;
    #pragma unroll
    for (int j = 0; j < 8; ++j) s += bf2f(uv.u[j]);
    s += __shfl_down(s, 4); s += __shfl_down(s, 2); s += __shfl_down(s, 1);
    if (g == 0) csl[c] = s;                      // unique c per (group,pass): plain store
  }
  __syncthreads();
  atomicAdd(&colsum[t], csl[t]);
}

// ---------- Gram pass: partial G = X^T X per block (bf16 MFMA, fp32 acc) ----------
// BF=1: stage xsT[c][m] from xT with pure 16B vector copies (no transpose, no f2bf).
// BF=0: legacy fallback (f32 x + colsum here) for small workspaces.
template<int BF>
__global__ __launch_bounds__(512, 2) void k_gram(const float* __restrict__ x,
                                                 const u16* __restrict__ xT,
                                                 float* __restrict__ Gp,
                                                 float* __restrict__ colsum) {
  __shared__ u16 xsT[256 * GP];    // 86016 B, [c][m] bf16, m padded 152..159 = 0
  __shared__ float scs[512];       // only used in BF=0
  int tid = threadIdx.x, bid = blockIdx.x;
  int c = tid & 255, mh = tid >> 8;
  int lane = tid & 63, wave = tid >> 6;
  int cl = lane & 15, q = lane >> 4;

  if (tid < 256) {   // zero pad columns m=152..159 once
    *reinterpret_cast<uint2*>(&xsT[tid * GP + 152]) = make_uint2(0u, 0u);
    *reinterpret_cast<uint2*>(&xsT[tid * GP + 156]) = make_uint2(0u, 0u);
  }

  float cs = 0.f;
  f32x4 acc[2][16];
  #pragma unroll
  for (int ri = 0; ri < 2; ++ri)
    #pragma unroll
    for (int j = 0; j < 16; ++j) acc[ri][j] = zero4();

  for (int ss = 0; ss < 4; ++ss) {
    int sl = bid * 4 + ss;
    __syncthreads();   // prev-slab reads done before overwrite (also orders pad-zero)
    if constexpr (BF) {
      const u16* xc = xT + (size_t)bid * 608 + ss * 152;
      #pragma unroll 1
      for (int i = tid; i < 4864; i += 512) {    // 256 c-rows x 19 granules of 16B
        int cc = i / 19, g = i - cc * 19;
        *reinterpret_cast<bf16x8*>(&xsT[cc * GP + g * 8]) =
            *reinterpret_cast<const bf16x8*>(&xc[(size_t)cc * 155648 + g * 8]);
      }
    } else {
      const float* xb = x + (size_t)sl * 152 * 256;
      #pragma unroll 1
      for (int it = 0; it < 19; ++it) {
        int m0 = it * 8 + mh * 4;
        float v0 = xb[(m0 + 0) * 256 + c];
        float v1 = xb[(m0 + 1) * 256 + c];
        float v2 = xb[(m0 + 2) * 256 + c];
        float v3 = xb[(m0 + 3) * 256 + c];
        cs += v0 + v1 + v2 + v3;
        uint2 p;
        p.x = (u32)f2bf(v0) | ((u32)f2bf(v1) << 16);
        p.y = (u32)f2bf(v2) | ((u32)f2bf(v3) << 16);
        *reinterpret_cast<uint2*>(&xsT[c * GP + m0]) = p;
      }
    }
    __syncthreads();
    // Gram MFMA: wave owns G tile-rows {wave, wave+8}, all 16 tile-cols
    #pragma unroll
    for (int s = 0; s < 5; ++s) {
      int kof = s * 32 + q * 8;
      bf16x8 a0 = *reinterpret_cast<const bf16x8*>(&xsT[(wave * 16 + cl) * GP + kof]);
      bf16x8 a1 = *reinterpret_cast<const bf16x8*>(&xsT[((wave + 8) * 16 + cl) * GP + kof]);
      #pragma unroll
      for (int ct2 = 0; ct2 < 16; ++ct2) {
        bf16x8 b = *reinterpret_cast<const bf16x8*>(&xsT[(ct2 * 16 + cl) * GP + kof]);
        acc[0][ct2] = __builtin_amdgcn_mfma_f32_16x16x32_bf16(a0, b, acc[0][ct2], 0, 0, 0);
        acc[1][ct2] = __builtin_amdgcn_mfma_f32_16x16x32_bf16(a1, b, acc[1][ct2], 0, 0, 0);
      }
    }
  }
  // emit upper triangle partials (plain stores; k_red sums + mirrors)
  #pragma unroll
  for (int ri = 0; ri < 2; ++ri) {
    int ct = wave + ri * 8;
    int tb = 16 * ct - (ct * (ct - 1)) / 2 - ct;   // tri = tb + ct2
    #pragma unroll
    for (int ct2 = 0; ct2 < 16; ++ct2) {
      if (ct2 >= ct) {
        float* dst = Gp + ((size_t)(tb + ct2) * 256 + bid) * 256;
        #pragma unroll
        for (int r4 = 0; r4 < 4; ++r4)
          dst[(q * 4 + r4) * 16 + cl] = acc[ri][ct2][r4];
      }
    }
  }
  if constexpr (!BF) {
    scs[tid] = cs;
    __syncthreads();
    if (tid < 256) atomicAdd(&colsum[tid], scs[tid] + scs[tid + 256]);
  }
}

// ---------- reduce partials -> G (both triangles; replaces k_sym) ----------
__global__ __launch_bounds__(256) void k_red(const float* __restrict__ Gp,
                                             float* __restrict__ G) {
  int b = blockIdx.x;           // 0..135 upper-triangle tile index
  int e = threadIdx.x;          // 0..255 element in 16x16 tile
  int ct = 0;
  #pragma unroll
  for (int t = 1; t < 16; ++t)
    if (b >= 16 * t - (t * (t - 1)) / 2) ct = t;
  int ct2 = ct + (b - (16 * ct - (ct * (ct - 1)) / 2));
  const float* src = Gp + (size_t)b * 65536;   // [256 partials][256 elems], contiguous
  float s = 0.f;
  #pragma unroll 8
  for (int p = 0; p < 256; ++p) s += src[p * 256 + e];
  int row = e >> 4, col = e & 15;
  int rr = ct * 16 + row, cc = ct2 * 16 + col;
  G[rr * 256 + cc] = s;
  G[cc * 256 + rr] = s;    // mirror (diagonal tiles: same address, same value)
}

// ---------- fold BN1: S,T per d from Gram quad-form ----------
__global__ __launch_bounds__(256) void k_f1(const float* __restrict__ G,
                                            const float* __restrict__ colsum,
                                            const float* __restrict__ W,
                                            const float* __restrict__ gam,
                                            const float* __restrict__ bet,
                                            float* __restrict__ ST) {
  __shared__ float wd[256];
  __shared__ float red[16];
  int d = blockIdx.x, c = threadIdx.x;
  float wv = W[c * 768 + d];
  wd[c] = wv;
  __syncthreads();
  float dot = 0.f;
  const float* Gr = G + c * 256;
  #pragma unroll 4
  for (int j = 0; j < 256; ++j) dot += Gr[j] * wd[j];
  float part = wv * dot;
  float mpart = colsum[c] * wv;
  #pragma unroll
  for (int o = 32; o; o >>= 1) { part += __shfl_down(part, o); mpart += __shfl_down(mpart, o); }
  int lane = c & 63, w = c >> 6;
  if (lane == 0) { red[w] = part; red[8 + w] = mpart; }
  __syncthreads();
  if (c == 0) {
    float qv = red[0] + red[1] + red[2] + red[3];
    float ms = red[8] + red[9] + red[10] + red[11];
    float mean = ms / M_ALL;
    float var = qv / M_ALL - mean * mean;
    float S = gam[d] * rsqrtf(var + 1e-5f);
    ST[d] = S;
    ST[768 + d] = bet[d] - mean * S;
  }
}

// ---------- main: GEMM + BN1 affine + adjacency MFMA + residual; write z; z-stats ----------
// 512 thr, (512,2): 128 arch VGPR + AGPRs on top, 1 block/CU, no spills. Occupancy >2
// waves/SIMD unreachable (caps 64/128/170 all spilled: rounds 1,3,4).
template<int BF>
__global__ __launch_bounds__(512, 2) void k_main(const float* __restrict__ x,
                                                 const u16* __restrict__ xbf,
                                                 const u16* __restrict__ wt,
                                                 const u16* __restrict__ wa2,
                                                 const float* __restrict__ ST,
                                                 float* __restrict__ sumz,
                                                 float* __restrict__ out) {
  __shared__ u16 xs[152 * 256];       // 77824 B, swizzled
  __shared__ u16 y2[512 * 64];        // 65536 B, [r=(t,c_local)][kvp] swizzled; reused as f32 zbuf
  __shared__ float scrz[1024];        // 4096 B stat scratch
  int tid = threadIdx.x;
  int bid = blockIdx.x;
  size_t obase = (size_t)bid * 152 * 256;

  if constexpr (BF) {  // stage from bf16: 16B granules, chunk-XOR applied on the SOURCE address
    const u16* xb16 = xbf + (size_t)bid * 152 * 256;
    int w = tid >> 6, lane = tid & 63;
    int ch = lane & 31, half = lane >> 5;
    for (int it = 0; it < 10; ++it) {
      int m = it * 16 + 2 * w + half;
      if (m < 152) {
        const u16* src = xb16 + m * 256 + ((ch ^ (m & 7)) << 3);
        *reinterpret_cast<bf16x8*>(&xs[m * 256 + (ch << 3)]) =
            *reinterpret_cast<const bf16x8*>(src);
      }
    }
  } else {             // legacy: f32 load + f2bf pack
    const float* xbase = x + (size_t)bid * 152 * 256;
    int r = tid >> 6, c4 = (tid & 63) << 2;
    for (int it = 0; it < 19; ++it) {
      int m = it * 8 + r;
      float4 f = *reinterpret_cast<const float4*>(xbase + m * 256 + c4);
      uint2 p;
      p.x = (u32)f2bf(f.x) | ((u32)f2bf(f.y) << 16);
      p.y = (u32)f2bf(f.z) | ((u32)f2bf(f.w) << 16);
      *reinterpret_cast<uint2*>(&xs[xs_idx(m, c4)]) = p;
    }
  }

  int lane = tid & 63, wave = tid >> 6;
  int mhalf = wave & 1, nt3 = wave >> 1;
  int cl = lane & 15, q = lane >> 4;
  int g = wave;                                  // adjacency: wave owns group g
  const bf16x8* wtv = reinterpret_cast<const bf16x8*>(wt);
  float* zbufF = reinterpret_cast<float*>(y2);   // [64 c][153 m] f32

  // adjacency B-frags: registers, loaded once from global (L2-hot)
  bf16x8 bfr[2][2];
  #pragma unroll
  for (int ks = 0; ks < 2; ++ks)
    #pragma unroll
    for (int nt = 0; nt < 2; ++nt) {
      int w = nt * 16 + cl; int wc = (w < 20) ? w : 19;
      bfr[ks][nt] = *reinterpret_cast<const bf16x8*>(&wa2[(g * 20 + wc) * 64 + ks * 32 + q * 8]);
    }

  int arow[5], mlow[5];
  #pragma unroll
  for (int i = 0; i < 5; ++i) {
    int rr = mhalf * 80 + i * 16 + cl;
    if (rr > 151) rr = 151;
    arow[i] = rr * 256; mlow[i] = rr & 7;
  }
  __syncthreads();

  for (int nc = 0; nc < 4; ++nc) {
    // ---- GEMM (regs only) ----
    f32x4 acc[5][3];
    #pragma unroll
    for (int i = 0; i < 5; ++i)
      #pragma unroll
      for (int jj = 0; jj < 3; ++jj) acc[i][jj] = zero4();
    for (int s = 0; s < 8; ++s) {
      int sq4 = s * 4 + q;
      bf16x8 b[3];
      #pragma unroll
      for (int jj = 0; jj < 3; ++jj) {
        int j = nt3 * 3 + jj;
        int d = (j >> 2) * 256 + nc * 64 + (j & 3) * 16 + cl;
        b[jj] = wtv[d * 32 + sq4];
      }
      #pragma unroll
      for (int i = 0; i < 5; ++i) {
        bf16x8 a = *reinterpret_cast<const bf16x8*>(&xs[arow[i] + ((sq4 ^ mlow[i]) << 3)]);
        #pragma unroll
        for (int jj = 0; jj < 3; ++jj)
          acc[i][jj] = __builtin_amdgcn_mfma_f32_16x16x32_bf16(a, b[jj], acc[i][jj], 0, 0, 0);
      }
    }
    __syncthreads();   // B0: prev-nc zbuf/scrz consumers done; y2 free

    // ---- re-zero kvp 57..63 (zbuf overlay clobbered them) ----
    #pragma unroll
    for (int kk = 0; kk < 7; ++kk)
      y2[y2_idx(tid, 57 + kk)] = 0;

    // ---- BN1 affine, pack bf16, write y2[(t,c_local)][kvp] ----
    #pragma unroll
    for (int jj = 0; jj < 3; ++jj) {
      int j = nt3 * 3 + jj;
      int ksub = j >> 2;
      int c_local = (j & 3) * 16 + cl;
      int d = ksub * 256 + nc * 64 + c_local;
      float Sc = ST[d], Tc = ST[768 + d];
      #pragma unroll
      for (int i = 0; i < 5; ++i) {
        int mb = mhalf * 80 + i * 16 + q * 4;
        #pragma unroll
        for (int r4 = 0; r4 < 4; ++r4) {
          int m = mb + r4;
          if (m < 152) {
            int t = (m * 27) >> 9;
            int v = m - t * 19;
            int kvp = ksub * 19 + v;
            int r = t * 64 + c_local;
            y2[y2_idx(r, kvp)] = f2bf(acc[i][jj][r4] * Sc + Tc);
          }
        }
      }
    }
    __syncthreads();   // B1: y2 complete

    // ---- adjacency MFMA: out1[(t,c8),w] = sum_kvp Y[(t,c8+8g... )][kvp] * A ----
    f32x4 zacc[4][2];
    #pragma unroll
    for (int mt = 0; mt < 4; ++mt) { zacc[mt][0] = zero4(); zacc[mt][1] = zero4(); }
    #pragma unroll
    for (int ks = 0; ks < 2; ++ks) {
      #pragma unroll
      for (int mt = 0; mt < 4; ++mt) {
        int tc = mt * 16 + cl;
        int t = tc >> 3, c8 = tc & 7;
        int r = t * 64 + c8 * 8 + g;
        int ch = (ks * 4 + q) ^ g ^ c8;
        bf16x8 afr = *reinterpret_cast<const bf16x8*>(&y2[r * 64 + (ch << 3)]);
        #pragma unroll
        for (int nt = 0; nt < 2; ++nt)
          zacc[mt][nt] = __builtin_amdgcn_mfma_f32_16x16x32_bf16(afr, bfr[ks][nt], zacc[mt][nt], 0, 0, 0);
      }
    }
    __syncthreads();   // B2: all y2 reads done

    // ---- spill out1 (f32) to zbuf ----
    #pragma unroll
    for (int mt = 0; mt < 4; ++mt)
      #pragma unroll
      for (int nt = 0; nt < 2; ++nt) {
        int w = nt * 16 + cl;
        if (w < 19) {
          #pragma unroll
          for (int r4 = 0; r4 < 4; ++r4) {
            int mm = mt * 16 + q * 4 + r4;
            int t = mm >> 3, c8 = mm & 7;
            zbufF[(c8 * 8 + g) * 153 + t * 19 + w] = zacc[mt][nt][r4];
          }
        }
      }
    __syncthreads();   // B3: zbuf complete

    // ---- z = out1 + x (residual), coalesced store, z-stats ----
    float sz = 0.f, sq = 0.f;
    int cloc = tid & 63;
    int cglob = nc * 64 + cloc;
    #pragma unroll 1
    for (int rep = 0; rep < 19; ++rep) {
      int mp = rep * 8 + (tid >> 6);
      float z = zbufF[cloc * 153 + mp] + bf2f(xs[xs_idx(mp, cglob)]);
      out[obase + (size_t)mp * 256 + cglob] = z;
      sz += z; sq += z * z;
    }
    scrz[(tid >> 6) * 64 + cloc] = sz;
    scrz[512 + (tid >> 6) * 64 + cloc] = sq;
    __syncthreads();   // B4: scratch complete
    if (tid < 128) {
      int comp = tid >> 6, c = tid & 63;
      float v = 0.f;
      #pragma unroll
      for (int h = 0; h < 8; ++h) v += scrz[comp * 512 + h * 64 + c];
      atomicAdd(&sumz[comp * 256 + nc * 64 + c], v);
    }
  }
}

// ---------- fold BN2 ----------
__global__ void k_f2(const float* __restrict__ statz, const float* __restrict__ gam,
                     const float* __restrict__ bet, float* __restrict__ S1T1) {
  int c = threadIdx.x;  // 256
  float inv = 1.f / M_ALL;
  float mz = statz[c] * inv;
  float qv = statz[256 + c] * inv;
  float var = qv - mz * mz;
  float Sc = gam[c] * rsqrtf(var + 1e-5f);
  S1T1[c] = Sc;
  S1T1[256 + c] = bet[c] - mz * Sc;
}

// ---------- BN2 affine + ReLU, in-place on d_out ----------
__global__ __launch_bounds__(256) void k_relu(float* __restrict__ out,
                                              const float* __restrict__ S1T1) {
  int tid = threadIdx.x;
  int lane = tid & 63;
  int wv = ((blockIdx.x << 8) + tid) >> 6;     // 0..8191 global wave id
  const float4* s14 = reinterpret_cast<const float4*>(S1T1);
  float4 sv = s14[lane], tv = s14[64 + lane];
  float4* o4 = reinterpret_cast<float4*>(out);
  #pragma unroll 1
  for (int r = 0; r < 19; ++r) {               // 155648 rows / 8192 waves
    size_t i = ((size_t)r * 8192 + wv) * 64 + lane;
    float4 f = o4[i];
    f.x = fmaxf(f.x * sv.x + tv.x, 0.f);
    f.y = fmaxf(f.y * sv.y + tv.y, 0.f);
    f.z = fmaxf(f.z * sv.z + tv.z, 0.f);
    f.w = fmaxf(f.w * sv.w + tv.w, 0.f);
    o4[i] = f;
  }
}

extern "C" void kernel_launch(void* const* d_in, const int* in_sizes, int n_in,
                              void* d_out, int out_size, void* d_ws, size_t ws_size,
                              hipStream_t stream) {
  const float* x    = (const float*)d_in[0];
  const float* para = (const float*)d_in[1];
  const float* W    = (const float*)d_in[2];
  // d_in[3] linear_bias: cancels through training-mode BN — unused
  const float* bng  = (const float*)d_in[4];
  const float* bnb  = (const float*)d_in[5];
  const float* bn1g = (const float*)d_in[6];
  const float* bn1b = (const float*)d_in[7];
  float* out = (float*)d_out;

  char* ws = (char*)d_ws;
  u16* wt     = (u16*)ws;                     // 393216 B
  u16* wa2    = (u16*)(ws + 393216);          // 20480 B
  float* G    = (float*)(ws + 413696);        // 262144 B
  float* csum = (float*)(ws + 675840);        // 1024 B
  float* sumz = (float*)(ws + 676864);        // 2048 B
  float* ST   = (float*)(ws + 678912);        // 6144 B
  float* S1T1 = (float*)(ws + 685056);        // 2048 B
  u16* xbf    = (u16*)(ws + 687104);          // 79691776 B (bf16 x, row-major)
  // d_out scratch phase (all dead before k_main writes z; stream-ordered):
  //   xT  [c][m] bf16 transpose at d_out+0       (79691776 B)  [k_tr -> k_gram]
  //   Gp  partial Gram at d_out+79691776         (35651584 B)  [k_gram -> k_red]
  u16* xT   = (u16*)d_out;
  float* Gp = (float*)((char*)d_out + 79691776);

  const size_t NEED = 687104u + 79691776u;

  hipMemsetAsync(ws + 675840, 0, 1024 + 2048, stream);   // colsum, sumz
  k_prep<<<dim3(1),    dim3(512), 0, stream>>>(para, wa2);
  k_wt  <<<dim3(384),  dim3(512), 0, stream>>>(W, wt);
  if (ws_size >= NEED) {
    k_tr  <<<dim3(2432), dim3(256), 0, stream>>>(x, xbf, xT, csum);
    k_gram<1><<<dim3(256),  dim3(512), 0, stream>>>(x, xT, Gp, csum);
    k_red <<<dim3(136),  dim3(256), 0, stream>>>(Gp, G);
    k_f1  <<<dim3(768),  dim3(256), 0, stream>>>(G, csum, W, bng, bnb, ST);
    k_main<1><<<dim3(1024), dim3(512), 0, stream>>>(x, xbf, wt, wa2, ST, sumz, out);
  } else {  // workspace too small for xbf: round-5 path (Gp at d_out base)
    float* Gp0 = (float*)d_out;
    k_gram<0><<<dim3(256),  dim3(512), 0, stream>>>(x, nullptr, Gp0, csum);
    k_red <<<dim3(136),  dim3(256), 0, stream>>>(Gp0, G);
    k_f1  <<<dim3(768),  dim3(256), 0, stream>>>(G, csum, W, bng, bnb, ST);
    k_main<0><<<dim3(1024), dim3(512), 0, stream>>>(x, nullptr, wt, wa2, ST, sumz, out);
  }
  k_f2  <<<dim3(1),    dim3(256), 0, stream>>>(sumz, bn1g, bn1b, S1T1);
  k_relu<<<dim3(2048), dim3(256), 0, stream>>>(out, S1T1);
}

// Round 8
// 657.177 us; speedup vs baseline: 1.1625x; 1.1625x over previous
//
#include <hip/hip_runtime.h>

typedef unsigned short u16;
typedef unsigned int u32;
typedef float f32x4 __attribute__((ext_vector_type(4)));
typedef __bf16 bf16x8 __attribute__((ext_vector_type(8)));

#define M_ALL 155648.0f
#define GP 168            // k_gram xsT pitch (u16): 84 dw stride -> 8-quad spread, 16B aligned

__device__ __forceinline__ u16 f2bf(float f) {
  union { float f; u32 u; } x; x.f = f;
  u32 u = x.u;
  u += 0x7FFFu + ((u >> 16) & 1u);   // RNE
  return (u16)(u >> 16);
}
__device__ __forceinline__ float bf2f(u16 h) {
  union { u32 u; float f; } x; x.u = ((u32)h) << 16;
  return x.f;
}
__device__ __forceinline__ f32x4 zero4() { f32x4 z = {0.f, 0.f, 0.f, 0.f}; return z; }

// xs swizzled index: row m (0..151), col c (0..255), 16B chunks XORed with m&7
__device__ __forceinline__ int xs_idx(int m, int c) {
  return m * 256 + ((((c >> 3) ^ (m & 7)) << 3) | (c & 7));
}
// Y2 swizzled index: row r (0..511), col kvp (0..63), chunk ^= (r&7)^((r>>3)&7)
__device__ __forceinline__ int y2_idx(int r, int kvp) {
  int sw = (r & 7) ^ ((r >> 3) & 7);
  return r * 64 + ((((kvp >> 3) ^ sw) << 3) | (kvp & 7));
}

// ---------- prep: L2-normalize adjacency rows, build wa2[g][w(20)][kvp(64)] bf16 ----------
__global__ void k_prep(const float* __restrict__ para, u16* __restrict__ wa2) {
  __shared__ float aL[3 * 8 * 19 * 19];
  int tid = threadIdx.x;
  if (tid < 456) {                                        // 3*8*19 rows
    int k = tid / 152, rem = tid % 152, g = rem / 19, v = rem % 19;
    int base = ((k * 8 + g) * 19 + v) * 19;
    float ss = 0.f;
    #pragma unroll
    for (int w = 0; w < 19; ++w) { float a = para[base + w]; ss += a * a; }
    float inv = 1.f / (sqrtf(ss) + 1e-4f);
    #pragma unroll
    for (int w = 0; w < 19; ++w) aL[base + w] = para[base + w] * inv;
  }
  __syncthreads();
  for (int i = tid; i < 8 * 20 * 64; i += 512) {
    int g = i / 1280, rem = i % 1280, w = rem >> 6, kvp = rem & 63;
    u16 val = 0;
    if (w < 19 && kvp < 57) {
      int k = kvp / 19, v = kvp - 19 * k;
      val = f2bf(aL[((k * 8 + g) * 19 + v) * 19 + w]);
    }
    wa2[i] = val;
  }
}

// ---------- transpose linear_weight (256x768 f32) -> Wt[d][c] bf16 ----------
__global__ void k_wt(const float* __restrict__ W, u16* __restrict__ wt) {
  int idx = blockIdx.x * 512 + threadIdx.x;   // exactly 196608
  int d = idx >> 8, c = idx & 255;
  wt[idx] = f2bf(W[c * 768 + d]);
}

// ---------- tr v2: x f32 -> xbf (row-major bf16) + xTt (k_gram-tiled col-major) + colsum ----
// Round-7 lesson: lane-major-m reads + scattered writes ran HBM at 1.16 TB/s (all granules
// 16-64 B semi-random). v2: one full row per wave-load (1024 B contiguous), xbf as 512 B
// wave-contiguous stores, LDS transpose ([m][c] pitch 258), xTt in 128 B granule runs.
// xTt layout [b][c][608] (b = k_gram block): each k_gram block reads CONTIGUOUS 311 KB.
__global__ __launch_bounds__(256) void k_tr(const float* __restrict__ x,
                                            u16* __restrict__ xbf,
                                            u16* __restrict__ xTt,
                                            float* __restrict__ colsum) {
  __shared__ u16 tl[64 * 258];     // [m_local][c], pitch 258 u16 -> bank = (m + c/2) % 32
  __shared__ float csA[1024];      // [wave][c] colsum partials
  int t = threadIdx.x;
  int l = t & 63, w = t >> 6;
  float s0 = 0.f, s1 = 0.f, s2 = 0.f, s3 = 0.f;   // lane owns c = 4l..4l+3 (fixed)
  const float4* x4 = reinterpret_cast<const float4*>(x);

  for (int tt = 0; tt < 4; ++tt) {
    int m0 = (blockIdx.x * 4 + tt) * 64;
    __syncthreads();               // prev tile's phase-B reads of tl done
    #pragma unroll 4
    for (int it = 0; it < 16; ++it) {
      int ml = it * 4 + w;
      int m = m0 + ml;
      float4 f = x4[(size_t)m * 64 + l];          // coalesced: one row per wave-load
      u16 b0 = f2bf(f.x), b1 = f2bf(f.y), b2 = f2bf(f.z), b3 = f2bf(f.w);
      s0 += f.x; s1 += f.y; s2 += f.z; s3 += f.w;
      ushort4 pk; pk.x = b0; pk.y = b1; pk.z = b2; pk.w = b3;
      *reinterpret_cast<ushort4*>(&xbf[(size_t)m * 256 + 4 * l]) = pk;  // 512 B/wave
      // LDS: two u32 stores (pitch 258 keeps 4-B alignment; bank spread via m term)
      u32 lo = (u32)b0 | ((u32)b1 << 16);
      u32 hi = (u32)b2 | ((u32)b3 << 16);
      *reinterpret_cast<u32*>(&tl[ml * 258 + 4 * l]) = lo;
      *reinterpret_cast<u32*>(&tl[ml * 258 + 4 * l + 2]) = hi;
    }
    __syncthreads();               // tl complete
    // phase B: lane (k=l>>3, g=l&7) emits granule g (m = m0+8g..+7) of column c
    int k = l >> 3, g = l & 7;
    #pragma unroll
    for (int p = 0; p < 8; ++p) {
      int c = p * 32 + w * 8 + k;
      union { u16 v[8]; bf16x8 v8; } uv;
      #pragma unroll
      for (int j = 0; j < 8; ++j) uv.v[j] = tl[(8 * g + j) * 258 + c];
      int mg = m0 + 8 * g;
      int b = mg / 608;            // 8-granules never straddle (608 % 8 == 0)
      int mm = mg - b * 608;
      // 8 consecutive lanes (same k) -> 128 B contiguous per column
      *reinterpret_cast<bf16x8*>(&xTt[((size_t)b * 256 + c) * 608 + mm]) = uv.v8;
    }
  }
  csA[w * 256 + 4 * l + 0] = s0;
  csA[w * 256 + 4 * l + 1] = s1;
  csA[w * 256 + 4 * l + 2] = s2;
  csA[w * 256 + 4 * l + 3] = s3;
  __syncthreads();
  float s = csA[t] + csA[256 + t] + csA[512 + t] + csA[768 + t];
  atomicAdd(&colsum[t], s);
}

// ---------- Gram pass: partial G = X^T X per block (bf16 MFMA, fp32 acc) ----------
// BF=1: stage xsT[c][m] from xTt (block's 311 KB contiguous region) via 16B copies.
// BF=0: legacy fallback (f32 x + colsum here) for small workspaces.
template<int BF>
__global__ __launch_bounds__(512, 2) void k_gram(const float* __restrict__ x,
                                                 const u16* __restrict__ xTt,
                                                 float* __restrict__ Gp,
                                                 float* __restrict__ colsum) {
  __shared__ u16 xsT[256 * GP];    // 86016 B, [c][m] bf16, m padded 152..159 = 0
  __shared__ float scs[512];       // only used in BF=0
  int tid = threadIdx.x, bid = blockIdx.x;
  int c = tid & 255, mh = tid >> 8;
  int lane = tid & 63, wave = tid >> 6;
  int cl = lane & 15, q = lane >> 4;

  if (tid < 256) {   // zero pad columns m=152..159 once
    *reinterpret_cast<uint2*>(&xsT[tid * GP + 152]) = make_uint2(0u, 0u);
    *reinterpret_cast<uint2*>(&xsT[tid * GP + 156]) = make_uint2(0u, 0u);
  }

  float cs = 0.f;
  f32x4 acc[2][16];
  #pragma unroll
  for (int ri = 0; ri < 2; ++ri)
    #pragma unroll
    for (int j = 0; j < 16; ++j) acc[ri][j] = zero4();

  for (int ss = 0; ss < 4; ++ss) {
    int sl = bid * 4 + ss;
    __syncthreads();   // prev-slab reads done before overwrite (also orders pad-zero)
    if constexpr (BF) {
      const u16* xc = xTt + (size_t)bid * 155648;   // this block's contiguous region
      #pragma unroll 1
      for (int i = tid; i < 4864; i += 512) {       // 256 c-rows x 19 granules of 16B
        int cc = i / 19, g = i - cc * 19;
        *reinterpret_cast<bf16x8*>(&xsT[cc * GP + g * 8]) =
            *reinterpret_cast<const bf16x8*>(&xc[cc * 608 + ss * 152 + g * 8]);
      }
    } else {
      const float* xb = x + (size_t)sl * 152 * 256;
      #pragma unroll 1
      for (int it = 0; it < 19; ++it) {
        int m0 = it * 8 + mh * 4;
        float v0 = xb[(m0 + 0) * 256 + c];
        float v1 = xb[(m0 + 1) * 256 + c];
        float v2 = xb[(m0 + 2) * 256 + c];
        float v3 = xb[(m0 + 3) * 256 + c];
        cs += v0 + v1 + v2 + v3;
        uint2 p;
        p.x = (u32)f2bf(v0) | ((u32)f2bf(v1) << 16);
        p.y = (u32)f2bf(v2) | ((u32)f2bf(v3) << 16);
        *reinterpret_cast<uint2*>(&xsT[c * GP + m0]) = p;
      }
    }
    __syncthreads();
    // Gram MFMA: wave owns G tile-rows {wave, wave+8}, all 16 tile-cols
    #pragma unroll
    for (int s = 0; s < 5; ++s) {
      int kof = s * 32 + q * 8;
      bf16x8 a0 = *reinterpret_cast<const bf16x8*>(&xsT[(wave * 16 + cl) * GP + kof]);
      bf16x8 a1 = *reinterpret_cast<const bf16x8*>(&xsT[((wave + 8) * 16 + cl) * GP + kof]);
      #pragma unroll
      for (int ct2 = 0; ct2 < 16; ++ct2) {
        bf16x8 b = *reinterpret_cast<const bf16x8*>(&xsT[(ct2 * 16 + cl) * GP + kof]);
        acc[0][ct2] = __builtin_amdgcn_mfma_f32_16x16x32_bf16(a0, b, acc[0][ct2], 0, 0, 0);
        acc[1][ct2] = __builtin_amdgcn_mfma_f32_16x16x32_bf16(a1, b, acc[1][ct2], 0, 0, 0);
      }
    }
  }
  // emit upper triangle partials (plain stores; k_red sums + mirrors)
  #pragma unroll
  for (int ri = 0; ri < 2; ++ri) {
    int ct = wave + ri * 8;
    int tb = 16 * ct - (ct * (ct - 1)) / 2 - ct;   // tri = tb + ct2
    #pragma unroll
    for (int ct2 = 0; ct2 < 16; ++ct2) {
      if (ct2 >= ct) {
        float* dst = Gp + ((size_t)(tb + ct2) * 256 + bid) * 256;
        #pragma unroll
        for (int r4 = 0; r4 < 4; ++r4)
          dst[(q * 4 + r4) * 16 + cl] = acc[ri][ct2][r4];
      }
    }
  }
  if constexpr (!BF) {
    scs[tid] = cs;
    __syncthreads();
    if (tid < 256) atomicAdd(&colsum[tid], scs[tid] + scs[tid + 256]);
  }
}

// ---------- reduce partials -> G (both triangles; replaces k_sym) ----------
__global__ __launch_bounds__(256) void k_red(const float* __restrict__ Gp,
                                             float* __restrict__ G) {
  int b = blockIdx.x;           // 0..135 upper-triangle tile index
  int e = threadIdx.x;          // 0..255 element in 16x16 tile
  int ct = 0;
  #pragma unroll
  for (int t = 1; t < 16; ++t)
    if (b >= 16 * t - (t * (t - 1)) / 2) ct = t;
  int ct2 = ct + (b - (16 * ct - (ct * (ct - 1)) / 2));
  const float* src = Gp + (size_t)b * 65536;   // [256 partials][256 elems], contiguous
  float s = 0.f;
  #pragma unroll 8
  for (int p = 0; p < 256; ++p) s += src[p * 256 + e];
  int row = e >> 4, col = e & 15;
  int rr = ct * 16 + row, cc = ct2 * 16 + col;
  G[rr * 256 + cc] = s;
  G[cc * 256 + rr] = s;    // mirror (diagonal tiles: same address, same value)
}

// ---------- fold BN1: S,T per d from Gram quad-form ----------
__global__ __launch_bounds__(256) void k_f1(const float* __restrict__ G,
                                            const float* __restrict__ colsum,
                                            const float* __restrict__ W,
                                            const float* __restrict__ gam,
                                            const float* __restrict__ bet,
                                            float* __restrict__ ST) {
  __shared__ float wd[256];
  __shared__ float red[16];
  int d = blockIdx.x, c = threadIdx.x;
  float wv = W[c * 768 + d];
  wd[c] = wv;
  __syncthreads();
  float dot = 0.f;
  const float* Gr = G + c * 256;
  #pragma unroll 4
  for (int j = 0; j < 256; ++j) dot += Gr[j] * wd[j];
  float part = wv * dot;
  float mpart = colsum[c] * wv;
  #pragma unroll
  for (int o = 32; o; o >>= 1) { part += __shfl_down(part, o); mpart += __shfl_down(mpart, o); }
  int lane = c & 63, w = c >> 6;
  if (lane == 0) { red[w] = part; red[8 + w] = mpart; }
  __syncthreads();
  if (c == 0) {
    float qv = red[0] + red[1] + red[2] + red[3];
    float ms = red[8] + red[9] + red[10] + red[11];
    float mean = ms / M_ALL;
    float var = qv / M_ALL - mean * mean;
    float S = gam[d] * rsqrtf(var + 1e-5f);
    ST[d] = S;
    ST[768 + d] = bet[d] - mean * S;
  }
}

// ---------- main: GEMM + BN1 affine + adjacency MFMA + residual; write z; z-stats ----------
// 512 thr, (512,2): 128 arch VGPR + AGPRs on top, 1 block/CU, no spills. Occupancy >2
// waves/SIMD unreachable (caps 64/128/170 all spilled: rounds 1,3,4).
template<int BF>
__global__ __launch_bounds__(512, 2) void k_main(const float* __restrict__ x,
                                                 const u16* __restrict__ xbf,
                                                 const u16* __restrict__ wt,
                                                 const u16* __restrict__ wa2,
                                                 const float* __restrict__ ST,
                                                 float* __restrict__ sumz,
                                                 float* __restrict__ out) {
  __shared__ u16 xs[152 * 256];       // 77824 B, swizzled
  __shared__ u16 y2[512 * 64];        // 65536 B, [r=(t,c_local)][kvp] swizzled; reused as f32 zbuf
  __shared__ float scrz[1024];        // 4096 B stat scratch
  int tid = threadIdx.x;
  int bid = blockIdx.x;
  size_t obase = (size_t)bid * 152 * 256;

  if constexpr (BF) {  // stage from bf16: 16B granules, chunk-XOR applied on the SOURCE address
    const u16* xb16 = xbf + (size_t)bid * 152 * 256;
    int w = tid >> 6, lane = tid & 63;
    int ch = lane & 31, half = lane >> 5;
    for (int it = 0; it < 10; ++it) {
      int m = it * 16 + 2 * w + half;
      if (m < 152) {
        const u16* src = xb16 + m * 256 + ((ch ^ (m & 7)) << 3);
        *reinterpret_cast<bf16x8*>(&xs[m * 256 + (ch << 3)]) =
            *reinterpret_cast<const bf16x8*>(src);
      }
    }
  } else {             // legacy: f32 load + f2bf pack
    const float* xbase = x + (size_t)bid * 152 * 256;
    int r = tid >> 6, c4 = (tid & 63) << 2;
    for (int it = 0; it < 19; ++it) {
      int m = it * 8 + r;
      float4 f = *reinterpret_cast<const float4*>(xbase + m * 256 + c4);
      uint2 p;
      p.x = (u32)f2bf(f.x) | ((u32)f2bf(f.y) << 16);
      p.y = (u32)f2bf(f.z) | ((u32)f2bf(f.w) << 16);
      *reinterpret_cast<uint2*>(&xs[xs_idx(m, c4)]) = p;
    }
  }

  int lane = tid & 63, wave = tid >> 6;
  int mhalf = wave & 1, nt3 = wave >> 1;
  int cl = lane & 15, q = lane >> 4;
  int g = wave;                                  // adjacency: wave owns group g
  const bf16x8* wtv = reinterpret_cast<const bf16x8*>(wt);
  float* zbufF = reinterpret_cast<float*>(y2);   // [64 c][153 m] f32

  // adjacency B-frags: registers, loaded once from global (L2-hot)
  bf16x8 bfr[2][2];
  #pragma unroll
  for (int ks = 0; ks < 2; ++ks)
    #pragma unroll
    for (int nt = 0; nt < 2; ++nt) {
      int w = nt * 16 + cl; int wc = (w < 20) ? w : 19;
      bfr[ks][nt] = *reinterpret_cast<const bf16x8*>(&wa2[(g * 20 + wc) * 64 + ks * 32 + q * 8]);
    }

  int arow[5], mlow[5];
  #pragma unroll
  for (int i = 0; i < 5; ++i) {
    int rr = mhalf * 80 + i * 16 + cl;
    if (rr > 151) rr = 151;
    arow[i] = rr * 256; mlow[i] = rr & 7;
  }
  __syncthreads();

  for (int nc = 0; nc < 4; ++nc) {
    // ---- GEMM (regs only) ----
    f32x4 acc[5][3];
    #pragma unroll
    for (int i = 0; i < 5; ++i)
      #pragma unroll
      for (int jj = 0; jj < 3; ++jj) acc[i][jj] = zero4();
    for (int s = 0; s < 8; ++s) {
      int sq4 = s * 4 + q;
      bf16x8 b[3];
      #pragma unroll
      for (int jj = 0; jj < 3; ++jj) {
        int j = nt3 * 3 + jj;
        int d = (j >> 2) * 256 + nc * 64 + (j & 3) * 16 + cl;
        b[jj] = wtv[d * 32 + sq4];
      }
      #pragma unroll
      for (int i = 0; i < 5; ++i) {
        bf16x8 a = *reinterpret_cast<const bf16x8*>(&xs[arow[i] + ((sq4 ^ mlow[i]) << 3)]);
        #pragma unroll
        for (int jj = 0; jj < 3; ++jj)
          acc[i][jj] = __builtin_amdgcn_mfma_f32_16x16x32_bf16(a, b[jj], acc[i][jj], 0, 0, 0);
      }
    }
    __syncthreads();   // B0: prev-nc zbuf/scrz consumers done; y2 free

    // ---- re-zero kvp 57..63 (zbuf overlay clobbered them) ----
    #pragma unroll
    for (int kk = 0; kk < 7; ++kk)
      y2[y2_idx(tid, 57 + kk)] = 0;

    // ---- BN1 affine, pack bf16, write y2[(t,c_local)][kvp] ----
    #pragma unroll
    for (int jj = 0; jj < 3; ++jj) {
      int j = nt3 * 3 + jj;
      int ksub = j >> 2;
      int c_local = (j & 3) * 16 + cl;
      int d = ksub * 256 + nc * 64 + c_local;
      float Sc = ST[d], Tc = ST[768 + d];
      #pragma unroll
      for (int i = 0; i < 5; ++i) {
        int mb = mhalf * 80 + i * 16 + q * 4;
        #pragma unroll
        for (int r4 = 0; r4 < 4; ++r4) {
          int m = mb + r4;
          if (m < 152) {
            int t = (m * 27) >> 9;
            int v = m - t * 19;
            int kvp = ksub * 19 + v;
            int r = t * 64 + c_local;
            y2[y2_idx(r, kvp)] = f2bf(acc[i][jj][r4] * Sc + Tc);
          }
        }
      }
    }
    __syncthreads();   // B1: y2 complete

    // ---- adjacency MFMA: out1[(t,c8),w] = sum_kvp Y[(t,c8+8g... )][kvp] * A ----
    f32x4 zacc[4][2];
    #pragma unroll
    for (int mt = 0; mt < 4; ++mt) { zacc[mt][0] = zero4(); zacc[mt][1] = zero4(); }
    #pragma unroll
    for (int ks = 0; ks < 2; ++ks) {
      #pragma unroll
      for (int mt = 0; mt < 4; ++mt) {
        int tc = mt * 16 + cl;
        int t = tc >> 3, c8 = tc & 7;
        int r = t * 64 + c8 * 8 + g;
        int ch = (ks * 4 + q) ^ g ^ c8;
        bf16x8 afr = *reinterpret_cast<const bf16x8*>(&y2[r * 64 + (ch << 3)]);
        #pragma unroll
        for (int nt = 0; nt < 2; ++nt)
          zacc[mt][nt] = __builtin_amdgcn_mfma_f32_16x16x32_bf16(afr, bfr[ks][nt], zacc[mt][nt], 0, 0, 0);
      }
    }
    __syncthreads();   // B2: all y2 reads done

    // ---- spill out1 (f32) to zbuf ----
    #pragma unroll
    for (int mt = 0; mt < 4; ++mt)
      #pragma unroll
      for (int nt = 0; nt < 2; ++nt) {
        int w = nt * 16 + cl;
        if (w < 19) {
          #pragma unroll
          for (int r4 = 0; r4 < 4; ++r4) {
            int mm = mt * 16 + q * 4 + r4;
            int t = mm >> 3, c8 = mm & 7;
            zbufF[(c8 * 8 + g) * 153 + t * 19 + w] = zacc[mt][nt][r4];
          }
        }
      }
    __syncthreads();   // B3: zbuf complete

    // ---- z = out1 + x (residual), coalesced store, z-stats ----
    float sz = 0.f, sq = 0.f;
    int cloc = tid & 63;
    int cglob = nc * 64 + cloc;
    #pragma unroll 1
    for (int rep = 0; rep < 19; ++rep) {
      int mp = rep * 8 + (tid >> 6);
      float z = zbufF[cloc * 153 + mp] + bf2f(xs[xs_idx(mp, cglob)]);
      out[obase + (size_t)mp * 256 + cglob] = z;
      sz += z; sq += z * z;
    }
    scrz[(tid >> 6) * 64 + cloc] = sz;
    scrz[512 + (tid >> 6) * 64 + cloc] = sq;
    __syncthreads();   // B4: scratch complete
    if (tid < 128) {
      int comp = tid >> 6, c = tid & 63;
      float v = 0.f;
      #pragma unroll
      for (int h = 0; h < 8; ++h) v += scrz[comp * 512 + h * 64 + c];
      atomicAdd(&sumz[comp * 256 + nc * 64 + c], v);
    }
  }
}

// ---------- fold BN2 ----------
__global__ void k_f2(const float* __restrict__ statz, const float* __restrict__ gam,
                     const float* __restrict__ bet, float* __restrict__ S1T1) {
  int c = threadIdx.x;  // 256
  float inv = 1.f / M_ALL;
  float mz = statz[c] * inv;
  float qv = statz[256 + c] * inv;
  float var = qv - mz * mz;
  float Sc = gam[c] * rsqrtf(var + 1e-5f);
  S1T1[c] = Sc;
  S1T1[256 + c] = bet[c] - mz * Sc;
}

// ---------- BN2 affine + ReLU, in-place on d_out ----------
__global__ __launch_bounds__(256) void k_relu(float* __restrict__ out,
                                              const float* __restrict__ S1T1) {
  int tid = threadIdx.x;
  int lane = tid & 63;
  int wv = ((blockIdx.x << 8) + tid) >> 6;     // 0..8191 global wave id
  const float4* s14 = reinterpret_cast<const float4*>(S1T1);
  float4 sv = s14[lane], tv = s14[64 + lane];
  float4* o4 = reinterpret_cast<float4*>(out);
  #pragma unroll 1
  for (int r = 0; r < 19; ++r) {               // 155648 rows / 8192 waves
    size_t i = ((size_t)r * 8192 + wv) * 64 + lane;
    float4 f = o4[i];
    f.x = fmaxf(f.x * sv.x + tv.x, 0.f);
    f.y = fmaxf(f.y * sv.y + tv.y, 0.f);
    f.z = fmaxf(f.z * sv.z + tv.z, 0.f);
    f.w = fmaxf(f.w * sv.w + tv.w, 0.f);
    o4[i] = f;
  }
}

extern "C" void kernel_launch(void* const* d_in, const int* in_sizes, int n_in,
                              void* d_out, int out_size, void* d_ws, size_t ws_size,
                              hipStream_t stream) {
  const float* x    = (const float*)d_in[0];
  const float* para = (const float*)d_in[1];
  const float* W    = (const float*)d_in[2];
  // d_in[3] linear_bias: cancels through training-mode BN — unused
  const float* bng  = (const float*)d_in[4];
  const float* bnb  = (const float*)d_in[5];
  const float* bn1g = (const float*)d_in[6];
  const float* bn1b = (const float*)d_in[7];
  float* out = (float*)d_out;

  char* ws = (char*)d_ws;
  u16* wt     = (u16*)ws;                     // 393216 B
  u16* wa2    = (u16*)(ws + 393216);          // 20480 B
  float* G    = (float*)(ws + 413696);        // 262144 B
  float* csum = (float*)(ws + 675840);        // 1024 B
  float* sumz = (float*)(ws + 676864);        // 2048 B
  float* ST   = (float*)(ws + 678912);        // 6144 B
  float* S1T1 = (float*)(ws + 685056);        // 2048 B
  u16* xbf    = (u16*)(ws + 687104);          // 79691776 B (bf16 x, row-major)
  // d_out scratch phase (all dead before k_main writes z; stream-ordered):
  //   xTt [b][c][608] bf16 at d_out+0            (79691776 B)  [k_tr -> k_gram]
  //   Gp  partial Gram at d_out+79691776         (35651584 B)  [k_gram -> k_red]
  u16* xTt  = (u16*)d_out;
  float* Gp = (float*)((char*)d_out + 79691776);

  const size_t NEED = 687104u + 79691776u;

  hipMemsetAsync(ws + 675840, 0, 1024 + 2048, stream);   // colsum, sumz
  k_prep<<<dim3(1),    dim3(512), 0, stream>>>(para, wa2);
  k_wt  <<<dim3(384),  dim3(512), 0, stream>>>(W, wt);
  if (ws_size >= NEED) {
    k_tr  <<<dim3(608),  dim3(256), 0, stream>>>(x, xbf, xTt, csum);
    k_gram<1><<<dim3(256),  dim3(512), 0, stream>>>(x, xTt, Gp, csum);
    k_red <<<dim3(136),  dim3(256), 0, stream>>>(Gp, G);
    k_f1  <<<dim3(768),  dim3(256), 0, stream>>>(G, csum, W, bng, bnb, ST);
    k_main<1><<<dim3(1024), dim3(512), 0, stream>>>(x, xbf, wt, wa2, ST, sumz, out);
  } else {  // workspace too small for xbf: round-5 path (Gp at d_out base)
    float* Gp0 = (float*)d_out;
    k_gram<0><<<dim3(256),  dim3(512), 0, stream>>>(x, nullptr, Gp0, csum);
    k_red <<<dim3(136),  dim3(256), 0, stream>>>(Gp0, G);
    k_f1  <<<dim3(768),  dim3(256), 0, stream>>>(G, csum, W, bng, bnb, ST);
    k_main<0><<<dim3(1024), dim3(512), 0, stream>>>(x, nullptr, wt, wa2, ST, sumz, out);
  }
  k_f2  <<<dim3(1),    dim3(256), 0, stream>>>(sumz, bn1g, bn1b, S1T1);
  k_relu<<<dim3(2048), dim3(256), 0, stream>>>(out, S1T1);
}

// Round 9
// 607.494 us; speedup vs baseline: 1.2575x; 1.0818x over previous
//
#include <hip/hip_runtime.h>

typedef unsigned short u16;
typedef unsigned int u32;
typedef float f32x4 __attribute__((ext_vector_type(4)));
typedef __bf16 bf16x8 __attribute__((ext_vector_type(8)));

#define M_ALL 155648.0f
#define GP 168            // k_gram0 xsT pitch (u16): 84 dw stride -> 8-quad spread, 16B aligned

__device__ __forceinline__ u16 f2bf(float f) {
  union { float f; u32 u; } x; x.f = f;
  u32 u = x.u;
  u += 0x7FFFu + ((u >> 16) & 1u);   // RNE
  return (u16)(u >> 16);
}
__device__ __forceinline__ float bf2f(u16 h) {
  union { u32 u; float f; } x; x.u = ((u32)h) << 16;
  return x.f;
}
__device__ __forceinline__ f32x4 zero4() { f32x4 z = {0.f, 0.f, 0.f, 0.f}; return z; }

// xs swizzled index: row m (0..151), col c (0..255), 16B chunks XORed with m&7
__device__ __forceinline__ int xs_idx(int m, int c) {
  return m * 256 + ((((c >> 3) ^ (m & 7)) << 3) | (c & 7));
}
// Y2 swizzled index: row r (0..511), col kvp (0..63), chunk ^= (r&7)^((r>>3)&7)
__device__ __forceinline__ int y2_idx(int r, int kvp) {
  int sw = (r & 7) ^ ((r >> 3) & 7);
  return r * 64 + ((((kvp >> 3) ^ sw) << 3) | (kvp & 7));
}

// ---------- prep: L2-normalize adjacency rows, build wa2[g][w(20)][kvp(64)] bf16 ----------
__global__ void k_prep(const float* __restrict__ para, u16* __restrict__ wa2) {
  __shared__ float aL[3 * 8 * 19 * 19];
  int tid = threadIdx.x;
  if (tid < 456) {                                        // 3*8*19 rows
    int k = tid / 152, rem = tid % 152, g = rem / 19, v = rem % 19;
    int base = ((k * 8 + g) * 19 + v) * 19;
    float ss = 0.f;
    #pragma unroll
    for (int w = 0; w < 19; ++w) { float a = para[base + w]; ss += a * a; }
    float inv = 1.f / (sqrtf(ss) + 1e-4f);
    #pragma unroll
    for (int w = 0; w < 19; ++w) aL[base + w] = para[base + w] * inv;
  }
  __syncthreads();
  for (int i = tid; i < 8 * 20 * 64; i += 512) {
    int g = i / 1280, rem = i % 1280, w = rem >> 6, kvp = rem & 63;
    u16 val = 0;
    if (w < 19 && kvp < 57) {
      int k = kvp / 19, v = kvp - 19 * k;
      val = f2bf(aL[((k * 8 + g) * 19 + v) * 19 + w]);
    }
    wa2[i] = val;
  }
}

// ---------- transpose linear_weight (256x768 f32) -> Wt[d][c] bf16 ----------
__global__ void k_wt(const float* __restrict__ W, u16* __restrict__ wt) {
  int idx = blockIdx.x * 512 + threadIdx.x;   // exactly 196608
  int d = idx >> 8, c = idx & 255;
  wt[idx] = f2bf(W[c * 768 + d]);
}

// ---------- trg: FUSED transpose + Gram. x f32 -> xbf bf16 + Gp partials + colsum ----------
// Round-8 lesson: k_tr wrote the col-major transpose to HBM (80 MB) and k_gram read it
// right back (80 MB) through a second barrier-serialized kernel (~270 us for the pair).
// Fused: per 64-row tile, transpose through LDS (k_tr's proven conflict-free phases) into
// tlT[c][m-chunks] and run the Gram MFMA immediately; acc[2][16] persists over 4 tiles
// (K=256/block; 608*256 = 155648 exactly, no pad). (512,2): 128 arch VGPR + 128 AGPR acc;
// register demand limits HW to 1 block/CU (no silent 2-block spill).
__global__ __launch_bounds__(512, 2) void k_trg(const float* __restrict__ x,
                                                u16* __restrict__ xbf,
                                                float* __restrict__ Gp,
                                                float* __restrict__ colsum) {
  __shared__ u16 tl[64 * 258];     // [m_local][c] row tile, pitch 258 (k_tr-proven)
  __shared__ u16 tlT[256 * 72];    // [c][8 chunk-slots of 8 m, XOR-swizzled], 16B-aligned rows
  __shared__ float csA[2048];      // [wave][c] colsum partials
  int tid = threadIdx.x, bid = blockIdx.x;
  int l = tid & 63, w = tid >> 6;          // lane, wave 0..7
  int cl = l & 15, q = l >> 4;
  int kk = l >> 3, g = l & 7;

  float s0 = 0.f, s1 = 0.f, s2 = 0.f, s3 = 0.f;   // lane owns c = 4l..4l+3
  f32x4 acc[2][16];
  #pragma unroll
  for (int ri = 0; ri < 2; ++ri)
    #pragma unroll
    for (int j = 0; j < 16; ++j) acc[ri][j] = zero4();

  const float4* x4 = reinterpret_cast<const float4*>(x);
  for (int tt = 0; tt < 4; ++tt) {
    int m0 = bid * 256 + tt * 64;
    __syncthreads();               // prev tile's tl/tlT consumers done
    // ---- phase A: 8 rows/wave, coalesced loads; xbf store; tl[m][c] write ----
    #pragma unroll
    for (int r = 0; r < 8; ++r) {
      int ml = r * 8 + w;
      int m = m0 + ml;
      float4 f = x4[(size_t)m * 64 + l];          // 1024 B contiguous per wave
      u16 b0 = f2bf(f.x), b1 = f2bf(f.y), b2 = f2bf(f.z), b3 = f2bf(f.w);
      s0 += f.x; s1 += f.y; s2 += f.z; s3 += f.w;
      ushort4 pk; pk.x = b0; pk.y = b1; pk.z = b2; pk.w = b3;
      *reinterpret_cast<ushort4*>(&xbf[(size_t)m * 256 + 4 * l]) = pk;  // 512 B/wave
      u32 lo = (u32)b0 | ((u32)b1 << 16);
      u32 hi = (u32)b2 | ((u32)b3 << 16);
      *reinterpret_cast<u32*>(&tl[ml * 258 + 4 * l]) = lo;
      *reinterpret_cast<u32*>(&tl[ml * 258 + 4 * l + 2]) = hi;
    }
    __syncthreads();               // tl complete
    // ---- phase B: column granules -> tlT (chunk slot g ^ (c&7); c&7 == kk) ----
    #pragma unroll
    for (int p = 0; p < 4; ++p) {
      int c = p * 64 + w * 8 + kk;
      union { u16 v[8]; bf16x8 v8; } uv;
      #pragma unroll
      for (int j = 0; j < 8; ++j) uv.v[j] = tl[(8 * g + j) * 258 + c];
      *reinterpret_cast<bf16x8*>(&tlT[c * 72 + 8 * (g ^ (c & 7))]) = uv.v8;
    }
    __syncthreads();               // tlT complete
    // ---- Gram MFMA on this tile (K=64: s=0,1; chunk = s*4+q) ----
    #pragma unroll
    for (int s = 0; s < 2; ++s) {
      int ch = s * 4 + q;
      int ca0 = w * 16 + cl;
      int ca1 = (w + 8) * 16 + cl;
      bf16x8 a0 = *reinterpret_cast<const bf16x8*>(&tlT[ca0 * 72 + 8 * (ch ^ (ca0 & 7))]);
      bf16x8 a1 = *reinterpret_cast<const bf16x8*>(&tlT[ca1 * 72 + 8 * (ch ^ (ca1 & 7))]);
      #pragma unroll
      for (int ct2 = 0; ct2 < 16; ++ct2) {
        int cb = ct2 * 16 + cl;
        bf16x8 b = *reinterpret_cast<const bf16x8*>(&tlT[cb * 72 + 8 * (ch ^ (cb & 7))]);
        acc[0][ct2] = __builtin_amdgcn_mfma_f32_16x16x32_bf16(a0, b, acc[0][ct2], 0, 0, 0);
        acc[1][ct2] = __builtin_amdgcn_mfma_f32_16x16x32_bf16(a1, b, acc[1][ct2], 0, 0, 0);
      }
    }
  }
  // ---- epilogue: upper-triangle partials (plain stores; k_red sums + mirrors) ----
  #pragma unroll
  for (int ri = 0; ri < 2; ++ri) {
    int ct = w + ri * 8;
    int tb = 16 * ct - (ct * (ct - 1)) / 2 - ct;   // tri = tb + ct2
    #pragma unroll
    for (int ct2 = 0; ct2 < 16; ++ct2) {
      if (ct2 >= ct) {
        float* dst = Gp + ((size_t)(tb + ct2) * 608 + bid) * 256;
        #pragma unroll
        for (int r4 = 0; r4 < 4; ++r4)
          dst[(q * 4 + r4) * 16 + cl] = acc[ri][ct2][r4];
      }
    }
  }
  csA[w * 256 + 4 * l + 0] = s0;
  csA[w * 256 + 4 * l + 1] = s1;
  csA[w * 256 + 4 * l + 2] = s2;
  csA[w * 256 + 4 * l + 3] = s3;
  __syncthreads();
  if (tid < 256) {
    float s = 0.f;
    #pragma unroll
    for (int h = 0; h < 8; ++h) s += csA[h * 256 + tid];
    atomicAdd(&colsum[tid], s);
  }
}

// ---------- Gram fallback (small workspace): f32 x staging + colsum, 256 partials ----------
__global__ __launch_bounds__(512, 2) void k_gram0(const float* __restrict__ x,
                                                  float* __restrict__ Gp,
                                                  float* __restrict__ colsum) {
  __shared__ u16 xsT[256 * GP];    // [c][m] bf16, m padded 152..159 = 0
  __shared__ float scs[512];
  int tid = threadIdx.x, bid = blockIdx.x;
  int c = tid & 255, mh = tid >> 8;
  int lane = tid & 63, wave = tid >> 6;
  int cl = lane & 15, q = lane >> 4;

  if (tid < 256) {
    *reinterpret_cast<uint2*>(&xsT[tid * GP + 152]) = make_uint2(0u, 0u);
    *reinterpret_cast<uint2*>(&xsT[tid * GP + 156]) = make_uint2(0u, 0u);
  }

  float cs = 0.f;
  f32x4 acc[2][16];
  #pragma unroll
  for (int ri = 0; ri < 2; ++ri)
    #pragma unroll
    for (int j = 0; j < 16; ++j) acc[ri][j] = zero4();

  for (int ss = 0; ss < 4; ++ss) {
    int sl = bid * 4 + ss;
    const float* xb = x + (size_t)sl * 152 * 256;
    __syncthreads();
    #pragma unroll 1
    for (int it = 0; it < 19; ++it) {
      int m0 = it * 8 + mh * 4;
      float v0 = xb[(m0 + 0) * 256 + c];
      float v1 = xb[(m0 + 1) * 256 + c];
      float v2 = xb[(m0 + 2) * 256 + c];
      float v3 = xb[(m0 + 3) * 256 + c];
      cs += v0 + v1 + v2 + v3;
      uint2 p;
      p.x = (u32)f2bf(v0) | ((u32)f2bf(v1) << 16);
      p.y = (u32)f2bf(v2) | ((u32)f2bf(v3) << 16);
      *reinterpret_cast<uint2*>(&xsT[c * GP + m0]) = p;
    }
    __syncthreads();
    #pragma unroll
    for (int s = 0; s < 5; ++s) {
      int kof = s * 32 + q * 8;
      bf16x8 a0 = *reinterpret_cast<const bf16x8*>(&xsT[(wave * 16 + cl) * GP + kof]);
      bf16x8 a1 = *reinterpret_cast<const bf16x8*>(&xsT[((wave + 8) * 16 + cl) * GP + kof]);
      #pragma unroll
      for (int ct2 = 0; ct2 < 16; ++ct2) {
        bf16x8 b = *reinterpret_cast<const bf16x8*>(&xsT[(ct2 * 16 + cl) * GP + kof]);
        acc[0][ct2] = __builtin_amdgcn_mfma_f32_16x16x32_bf16(a0, b, acc[0][ct2], 0, 0, 0);
        acc[1][ct2] = __builtin_amdgcn_mfma_f32_16x16x32_bf16(a1, b, acc[1][ct2], 0, 0, 0);
      }
    }
  }
  #pragma unroll
  for (int ri = 0; ri < 2; ++ri) {
    int ct = wave + ri * 8;
    int tb = 16 * ct - (ct * (ct - 1)) / 2 - ct;
    #pragma unroll
    for (int ct2 = 0; ct2 < 16; ++ct2) {
      if (ct2 >= ct) {
        float* dst = Gp + ((size_t)(tb + ct2) * 256 + bid) * 256;
        #pragma unroll
        for (int r4 = 0; r4 < 4; ++r4)
          dst[(q * 4 + r4) * 16 + cl] = acc[ri][ct2][r4];
      }
    }
  }
  scs[tid] = cs;
  __syncthreads();
  if (tid < 256) atomicAdd(&colsum[tid], scs[tid] + scs[tid + 256]);
}

// ---------- reduce partials -> G (both triangles), 4 blocks per tile, atomic into zeroed G ----
__global__ __launch_bounds__(256) void k_red(const float* __restrict__ Gp,
                                             float* __restrict__ G, int npart) {
  int bx = blockIdx.x;          // 136 tiles x 4 p-splits
  int b = bx >> 2, h = bx & 3;
  int e = threadIdx.x;
  int ct = 0;
  #pragma unroll
  for (int t = 1; t < 16; ++t)
    if (b >= 16 * t - (t * (t - 1)) / 2) ct = t;
  int ct2 = ct + (b - (16 * ct - (ct * (ct - 1)) / 2));
  const float* src = Gp + (size_t)b * npart * 256;
  int pl = npart >> 2;
  float s = 0.f;
  #pragma unroll 8
  for (int i = 0; i < pl; ++i) s += src[(size_t)(h * pl + i) * 256 + e];
  int row = e >> 4, col = e & 15;
  int rr = ct * 16 + row, cc = ct2 * 16 + col;
  atomicAdd(&G[rr * 256 + cc], s);
  if (ct != ct2) atomicAdd(&G[cc * 256 + rr], s);   // diagonal tiles self-cover the mirror
}

// ---------- fold BN1: S,T per d from Gram quad-form ----------
__global__ __launch_bounds__(256) void k_f1(const float* __restrict__ G,
                                            const float* __restrict__ colsum,
                                            const float* __restrict__ W,
                                            const float* __restrict__ gam,
                                            const float* __restrict__ bet,
                                            float* __restrict__ ST) {
  __shared__ float wd[256];
  __shared__ float red[16];
  int d = blockIdx.x, c = threadIdx.x;
  float wv = W[c * 768 + d];
  wd[c] = wv;
  __syncthreads();
  float dot = 0.f;
  const float* Gr = G + c * 256;
  #pragma unroll 4
  for (int j = 0; j < 256; ++j) dot += Gr[j] * wd[j];
  float part = wv * dot;
  float mpart = colsum[c] * wv;
  #pragma unroll
  for (int o = 32; o; o >>= 1) { part += __shfl_down(part, o); mpart += __shfl_down(mpart, o); }
  int lane = c & 63, w = c >> 6;
  if (lane == 0) { red[w] = part; red[8 + w] = mpart; }
  __syncthreads();
  if (c == 0) {
    float qv = red[0] + red[1] + red[2] + red[3];
    float ms = red[8] + red[9] + red[10] + red[11];
    float mean = ms / M_ALL;
    float var = qv / M_ALL - mean * mean;
    float S = gam[d] * rsqrtf(var + 1e-5f);
    ST[d] = S;
    ST[768 + d] = bet[d] - mean * S;
  }
}

// ---------- main: GEMM + BN1 affine + adjacency MFMA + residual; write z; z-stats ----------
// 512 thr, (512,2): 128 arch VGPR + AGPRs on top, 1 block/CU, no spills. Occupancy >2
// waves/SIMD unreachable (caps 64/128/170 all spilled: rounds 1,3,4).
template<int BF>
__global__ __launch_bounds__(512, 2) void k_main(const float* __restrict__ x,
                                                 const u16* __restrict__ xbf,
                                                 const u16* __restrict__ wt,
                                                 const u16* __restrict__ wa2,
                                                 const float* __restrict__ ST,
                                                 float* __restrict__ sumz,
                                                 float* __restrict__ out) {
  __shared__ u16 xs[152 * 256];       // 77824 B, swizzled
  __shared__ u16 y2[512 * 64];        // 65536 B, [r=(t,c_local)][kvp] swizzled; reused as f32 zbuf
  __shared__ float scrz[1024];        // 4096 B stat scratch
  int tid = threadIdx.x;
  int bid = blockIdx.x;
  size_t obase = (size_t)bid * 152 * 256;

  if constexpr (BF) {  // stage from bf16: 16B granules, chunk-XOR applied on the SOURCE address
    const u16* xb16 = xbf + (size_t)bid * 152 * 256;
    int w = tid >> 6, lane = tid & 63;
    int ch = lane & 31, half = lane >> 5;
    for (int it = 0; it < 10; ++it) {
      int m = it * 16 + 2 * w + half;
      if (m < 152) {
        const u16* src = xb16 + m * 256 + ((ch ^ (m & 7)) << 3);
        *reinterpret_cast<bf16x8*>(&xs[m * 256 + (ch << 3)]) =
            *reinterpret_cast<const bf16x8*>(src);
      }
    }
  } else {             // legacy: f32 load + f2bf pack
    const float* xbase = x + (size_t)bid * 152 * 256;
    int r = tid >> 6, c4 = (tid & 63) << 2;
    for (int it = 0; it < 19; ++it) {
      int m = it * 8 + r;
      float4 f = *reinterpret_cast<const float4*>(xbase + m * 256 + c4);
      uint2 p;
      p.x = (u32)f2bf(f.x) | ((u32)f2bf(f.y) << 16);
      p.y = (u32)f2bf(f.z) | ((u32)f2bf(f.w) << 16);
      *reinterpret_cast<uint2*>(&xs[xs_idx(m, c4)]) = p;
    }
  }

  int lane = tid & 63, wave = tid >> 6;
  int mhalf = wave & 1, nt3 = wave >> 1;
  int cl = lane & 15, q = lane >> 4;
  int g = wave;                                  // adjacency: wave owns group g
  const bf16x8* wtv = reinterpret_cast<const bf16x8*>(wt);
  float* zbufF = reinterpret_cast<float*>(y2);   // [64 c][153 m] f32

  // adjacency B-frags: registers, loaded once from global (L2-hot)
  bf16x8 bfr[2][2];
  #pragma unroll
  for (int ks = 0; ks < 2; ++ks)
    #pragma unroll
    for (int nt = 0; nt < 2; ++nt) {
      int w = nt * 16 + cl; int wc = (w < 20) ? w : 19;
      bfr[ks][nt] = *reinterpret_cast<const bf16x8*>(&wa2[(g * 20 + wc) * 64 + ks * 32 + q * 8]);
    }

  int arow[5], mlow[5];
  #pragma unroll
  for (int i = 0; i < 5; ++i) {
    int rr = mhalf * 80 + i * 16 + cl;
    if (rr > 151) rr = 151;
    arow[i] = rr * 256; mlow[i] = rr & 7;
  }
  __syncthreads();

  for (int nc = 0; nc < 4; ++nc) {
    // ---- GEMM (regs only) ----
    f32x4 acc[5][3];
    #pragma unroll
    for (int i = 0; i < 5; ++i)
      #pragma unroll
      for (int jj = 0; jj < 3; ++jj) acc[i][jj] = zero4();
    for (int s = 0; s < 8; ++s) {
      int sq4 = s * 4 + q;
      bf16x8 b[3];
      #pragma unroll
      for (int jj = 0; jj < 3; ++jj) {
        int j = nt3 * 3 + jj;
        int d = (j >> 2) * 256 + nc * 64 + (j & 3) * 16 + cl;
        b[jj] = wtv[d * 32 + sq4];
      }
      #pragma unroll
      for (int i = 0; i < 5; ++i) {
        bf16x8 a = *reinterpret_cast<const bf16x8*>(&xs[arow[i] + ((sq4 ^ mlow[i]) << 3)]);
        #pragma unroll
        for (int jj = 0; jj < 3; ++jj)
          acc[i][jj] = __builtin_amdgcn_mfma_f32_16x16x32_bf16(a, b[jj], acc[i][jj], 0, 0, 0);
      }
    }
    __syncthreads();   // B0: prev-nc zbuf/scrz consumers done; y2 free

    // ---- re-zero kvp 57..63 (zbuf overlay clobbered them) ----
    #pragma unroll
    for (int kk = 0; kk < 7; ++kk)
      y2[y2_idx(tid, 57 + kk)] = 0;

    // ---- BN1 affine, pack bf16, write y2[(t,c_local)][kvp] ----
    #pragma unroll
    for (int jj = 0; jj < 3; ++jj) {
      int j = nt3 * 3 + jj;
      int ksub = j >> 2;
      int c_local = (j & 3) * 16 + cl;
      int d = ksub * 256 + nc * 64 + c_local;
      float Sc = ST[d], Tc = ST[768 + d];
      #pragma unroll
      for (int i = 0; i < 5; ++i) {
        int mb = mhalf * 80 + i * 16 + q * 4;
        #pragma unroll
        for (int r4 = 0; r4 < 4; ++r4) {
          int m = mb + r4;
          if (m < 152) {
            int t = (m * 27) >> 9;
            int v = m - t * 19;
            int kvp = ksub * 19 + v;
            int r = t * 64 + c_local;
            y2[y2_idx(r, kvp)] = f2bf(acc[i][jj][r4] * Sc + Tc);
          }
        }
      }
    }
    __syncthreads();   // B1: y2 complete

    // ---- adjacency MFMA: out1[(t,c8),w] = sum_kvp Y[(t,c8+8g... )][kvp] * A ----
    f32x4 zacc[4][2];
    #pragma unroll
    for (int mt = 0; mt < 4; ++mt) { zacc[mt][0] = zero4(); zacc[mt][1] = zero4(); }
    #pragma unroll
    for (int ks = 0; ks < 2; ++ks) {
      #pragma unroll
      for (int mt = 0; mt < 4; ++mt) {
        int tc = mt * 16 + cl;
        int t = tc >> 3, c8 = tc & 7;
        int r = t * 64 + c8 * 8 + g;
        int ch = (ks * 4 + q) ^ g ^ c8;
        bf16x8 afr = *reinterpret_cast<const bf16x8*>(&y2[r * 64 + (ch << 3)]);
        #pragma unroll
        for (int nt = 0; nt < 2; ++nt)
          zacc[mt][nt] = __builtin_amdgcn_mfma_f32_16x16x32_bf16(afr, bfr[ks][nt], zacc[mt][nt], 0, 0, 0);
      }
    }
    __syncthreads();   // B2: all y2 reads done

    // ---- spill out1 (f32) to zbuf ----
    #pragma unroll
    for (int mt = 0; mt < 4; ++mt)
      #pragma unroll
      for (int nt = 0; nt < 2; ++nt) {
        int w = nt * 16 + cl;
        if (w < 19) {
          #pragma unroll
          for (int r4 = 0; r4 < 4; ++r4) {
            int mm = mt * 16 + q * 4 + r4;
            int t = mm >> 3, c8 = mm & 7;
            zbufF[(c8 * 8 + g) * 153 + t * 19 + w] = zacc[mt][nt][r4];
          }
        }
      }
    __syncthreads();   // B3: zbuf complete

    // ---- z = out1 + x (residual), coalesced store, z-stats ----
    float sz = 0.f, sq = 0.f;
    int cloc = tid & 63;
    int cglob = nc * 64 + cloc;
    #pragma unroll 1
    for (int rep = 0; rep < 19; ++rep) {
      int mp = rep * 8 + (tid >> 6);
      float z = zbufF[cloc * 153 + mp] + bf2f(xs[xs_idx(mp, cglob)]);
      out[obase + (size_t)mp * 256 + cglob] = z;
      sz += z; sq += z * z;
    }
    scrz[(tid >> 6) * 64 + cloc] = sz;
    scrz[512 + (tid >> 6) * 64 + cloc] = sq;
    __syncthreads();   // B4: scratch complete
    if (tid < 128) {
      int comp = tid >> 6, c = tid & 63;
      float v = 0.f;
      #pragma unroll
      for (int h = 0; h < 8; ++h) v += scrz[comp * 512 + h * 64 + c];
      atomicAdd(&sumz[comp * 256 + nc * 64 + c], v);
    }
  }
}

// ---------- fold BN2 ----------
__global__ void k_f2(const float* __restrict__ statz, const float* __restrict__ gam,
                     const float* __restrict__ bet, float* __restrict__ S1T1) {
  int c = threadIdx.x;  // 256
  float inv = 1.f / M_ALL;
  float mz = statz[c] * inv;
  float qv = statz[256 + c] * inv;
  float var = qv - mz * mz;
  float Sc = gam[c] * rsqrtf(var + 1e-5f);
  S1T1[c] = Sc;
  S1T1[256 + c] = bet[c] - mz * Sc;
}

// ---------- BN2 affine + ReLU, in-place on d_out ----------
__global__ __launch_bounds__(256) void k_relu(float* __restrict__ out,
                                              const float* __restrict__ S1T1) {
  int tid = threadIdx.x;
  int lane = tid & 63;
  int wv = ((blockIdx.x << 8) + tid) >> 6;     // 0..8191 global wave id
  const float4* s14 = reinterpret_cast<const float4*>(S1T1);
  float4 sv = s14[lane], tv = s14[64 + lane];
  float4* o4 = reinterpret_cast<float4*>(out);
  #pragma unroll 1
  for (int r = 0; r < 19; ++r) {               // 155648 rows / 8192 waves
    size_t i = ((size_t)r * 8192 + wv) * 64 + lane;
    float4 f = o4[i];
    f.x = fmaxf(f.x * sv.x + tv.x, 0.f);
    f.y = fmaxf(f.y * sv.y + tv.y, 0.f);
    f.z = fmaxf(f.z * sv.z + tv.z, 0.f);
    f.w = fmaxf(f.w * sv.w + tv.w, 0.f);
    o4[i] = f;
  }
}

extern "C" void kernel_launch(void* const* d_in, const int* in_sizes, int n_in,
                              void* d_out, int out_size, void* d_ws, size_t ws_size,
                              hipStream_t stream) {
  const float* x    = (const float*)d_in[0];
  const float* para = (const float*)d_in[1];
  const float* W    = (const float*)d_in[2];
  // d_in[3] linear_bias: cancels through training-mode BN — unused
  const float* bng  = (const float*)d_in[4];
  const float* bnb  = (const float*)d_in[5];
  const float* bn1g = (const float*)d_in[6];
  const float* bn1b = (const float*)d_in[7];
  float* out = (float*)d_out;

  char* ws = (char*)d_ws;
  u16* wt     = (u16*)ws;                     // 393216 B
  u16* wa2    = (u16*)(ws + 393216);          // 20480 B
  float* G    = (float*)(ws + 413696);        // 262144 B
  float* csum = (float*)(ws + 675840);        // 1024 B
  float* sumz = (float*)(ws + 676864);        // 2048 B
  float* ST   = (float*)(ws + 678912);        // 6144 B
  float* S1T1 = (float*)(ws + 685056);        // 2048 B
  u16* xbf    = (u16*)(ws + 687104);          // 79691776 B (bf16 x, row-major)
  // d_out scratch phase: Gp partials (fused: 136*608*256*4 = 84.67 MB; fallback:
  // 136*256*256*4 = 35.7 MB), dead before k_main writes z (stream-ordered).
  float* Gp = (float*)d_out;

  const size_t NEED = 687104u + 79691776u;

  // zero G (k_red accumulates atomically) + colsum + sumz — contiguous range
  hipMemsetAsync(ws + 413696, 0, 262144 + 1024 + 2048, stream);
  k_prep<<<dim3(1),    dim3(512), 0, stream>>>(para, wa2);
  k_wt  <<<dim3(384),  dim3(512), 0, stream>>>(W, wt);
  if (ws_size >= NEED) {
    k_trg <<<dim3(608),  dim3(512), 0, stream>>>(x, xbf, Gp, csum);
    k_red <<<dim3(544),  dim3(256), 0, stream>>>(Gp, G, 608);
    k_f1  <<<dim3(768),  dim3(256), 0, stream>>>(G, csum, W, bng, bnb, ST);
    k_main<1><<<dim3(1024), dim3(512), 0, stream>>>(x, xbf, wt, wa2, ST, sumz, out);
  } else {  // workspace too small for xbf: f32 path
    k_gram0<<<dim3(256), dim3(512), 0, stream>>>(x, Gp, csum);
    k_red <<<dim3(544),  dim3(256), 0, stream>>>(Gp, G, 256);
    k_f1  <<<dim3(768),  dim3(256), 0, stream>>>(G, csum, W, bng, bnb, ST);
    k_main<0><<<dim3(1024), dim3(512), 0, stream>>>(x, nullptr, wt, wa2, ST, sumz, out);
  }
  k_f2  <<<dim3(1),    dim3(256), 0, stream>>>(sumz, bn1g, bn1b, S1T1);
  k_relu<<<dim3(2048), dim3(256), 0, stream>>>(out, S1T1);
}